// Round 22
// baseline (110.582 us; speedup 1.0000x reference)
//
#include <hip/hip_runtime.h>

#define K_CL  1024
#define D_DIM 256
#define BN    128                 // rows per block (4 waves x 32 rows)
#define CTILE 64                  // cols per staged LDS tile (32 KB)
#define NCT   (K_CL / CTILE)      // 16 tiles
#define GPT   (CTILE * 32 / 256)  // gload_lds16 per thread per stage = 8

typedef __attribute__((ext_vector_type(8))) short bf16x8;
typedef __attribute__((ext_vector_type(4))) float f32x4;

// ---------- fp32 -> bf16 round-to-nearest-even ----------
__device__ __forceinline__ short f2bf(float f) {
    unsigned b = __float_as_uint(f);
    unsigned r = (b + 0x7FFFu + ((b >> 16) & 1u)) >> 16;
    return (short)r;
}

// ---------- async global->LDS, 16B per lane ----------
__device__ __forceinline__ void gload_lds16(const void* g, void* l) {
    __builtin_amdgcn_global_load_lds(
        (const __attribute__((address_space(1))) unsigned int*)g,
        (__attribute__((address_space(3))) unsigned int*)l, 16, 0, 0);
}

// ---------- numpy pairwise sum-of-squares (np-exact; contract(off) forbids fma) ----------
template <typename F>
__device__ float np_pairwise_half(F ld, int base4) {
#pragma clang fp contract(off)
    float4 f0 = ld(base4 + 0);
    float4 f1 = ld(base4 + 1);
    float r0 = __fmul_rn(f0.x, f0.x), r1 = __fmul_rn(f0.y, f0.y);
    float r2 = __fmul_rn(f0.z, f0.z), r3 = __fmul_rn(f0.w, f0.w);
    float r4 = __fmul_rn(f1.x, f1.x), r5 = __fmul_rn(f1.y, f1.y);
    float r6 = __fmul_rn(f1.z, f1.z), r7 = __fmul_rn(f1.w, f1.w);
    #pragma unroll
    for (int p = 1; p < 16; ++p) {
        float4 a = ld(base4 + 2 * p);
        float4 b = ld(base4 + 2 * p + 1);
        r0 = __fadd_rn(r0, __fmul_rn(a.x, a.x)); r1 = __fadd_rn(r1, __fmul_rn(a.y, a.y));
        r2 = __fadd_rn(r2, __fmul_rn(a.z, a.z)); r3 = __fadd_rn(r3, __fmul_rn(a.w, a.w));
        r4 = __fadd_rn(r4, __fmul_rn(b.x, b.x)); r5 = __fadd_rn(r5, __fmul_rn(b.y, b.y));
        r6 = __fadd_rn(r6, __fmul_rn(b.z, b.z)); r7 = __fadd_rn(r7, __fmul_rn(b.w, b.w));
    }
    return __fadd_rn(__fadd_rn(__fadd_rn(r0, r1), __fadd_rn(r2, r3)),
                     __fadd_rn(__fadd_rn(r4, r5), __fadd_rn(r6, r7)));
}

// ---- kernel 1: cvt (C fp32 -> swizzled bf16) + c2 (blocks 0..7) ----
__global__ void prep_kernel(const float* __restrict__ C, short* __restrict__ Cs,
                            float* __restrict__ c2) {
#pragma clang fp contract(off)
    int d    = blockIdx.x * 256 + threadIdx.x;     // 0..32767
    int n    = d >> 9;
    int r    = d & 511;
    int ks   = r >> 6;
    int kg   = (r >> 4) & 3;
    int lo   = r & 15;
    int col  = n * 16 + lo;
    const float* src = C + (size_t)col * D_DIM + ks * 32 + kg * 8;
    float4 a = *reinterpret_cast<const float4*>(src);
    float4 b = *reinterpret_cast<const float4*>(src + 4);
    bf16x8 o;
    o[0] = f2bf(a.x); o[1] = f2bf(a.y); o[2] = f2bf(a.z); o[3] = f2bf(a.w);
    o[4] = f2bf(b.x); o[5] = f2bf(b.y); o[6] = f2bf(b.z); o[7] = f2bf(b.w);
    reinterpret_cast<bf16x8*>(Cs)[d] = o;

    if (blockIdx.x < 8) {
        int id   = blockIdx.x * 128 + (threadIdx.x >> 1);   // row k
        int half = threadIdx.x & 1;
        const float4* row = reinterpret_cast<const float4*>(C) + (size_t)id * 64;
        auto ld = [&](int d4) { return row[d4]; };
        float v = np_pairwise_half(ld, half * 32);
        float other = __shfl_xor(v, 1);
        if (half == 0) c2[id] = __fadd_rn(v, other);
    }
}

// ---- kernel 2: fused gemm (dbuf issue-early staging + pipelined insert)
//      + np-exact rescore (2-chain interleaved) + gather ----
__launch_bounds__(256, 2)
__global__ void kmeans_fused(const float* __restrict__ X, const float* __restrict__ C,
                             const short* __restrict__ Cswz, const float* __restrict__ c2g,
                             float* __restrict__ out) {
#pragma clang fp contract(off)
    __shared__ bf16x8   Bs[2][CTILE * 32];   // 2 x 32 KB double buffer
    __shared__ float    c2s[K_CL];           // 4 KB, pre-offset by +32
    __shared__ float    x2L[BN];
    __shared__ unsigned candL[BN][4];
    __shared__ int      asgL[BN];

    const int tid  = threadIdx.x;
    const int w    = tid >> 6;               // wave 0..3
    const int l    = tid & 63;
    const int lo16 = l & 15;
    const int kg   = l >> 4;
    const int blk_row0  = blockIdx.x * BN;
    const int wave_row0 = blk_row0 + w * 32; // 32 rows per wave (2 m-frags)

    const bf16x8* Cs8 = reinterpret_cast<const bf16x8*>(Cswz);

    // stage one 64-col tile (32 KB): 8 gload_lds16 per thread, contiguous
    #define STAGE(b, T) { \
        const bf16x8* gsrc = Cs8 + (size_t)(T) * (CTILE * 32); \
        _Pragma("unroll") \
        for (int c = 0; c < GPT; ++c) \
            gload_lds16(&gsrc[c * 256 + tid], &Bs[b][c * 256 + tid]); }

    STAGE(0, 0);                             // issue tile 0 under the prologue

    // c2s with +32 offset: scores provably positive -> float bits monotone
    #pragma unroll
    for (int i = 0; i < 4; ++i) c2s[tid + i * 256] = __fadd_rn(c2g[tid + i * 256], 32.0f);

    // ---- resident A fragments ----
    bf16x8 af[2][8];
    #pragma unroll
    for (int m = 0; m < 2; ++m)
        #pragma unroll
        for (int ks = 0; ks < 8; ++ks) {
            const float* xr = X + (size_t)(wave_row0 + m * 16 + lo16) * D_DIM + ks * 32 + kg * 8;
            float4 u = *reinterpret_cast<const float4*>(xr);
            float4 v = *reinterpret_cast<const float4*>(xr + 4);
            bf16x8 o;
            o[0] = f2bf(u.x); o[1] = f2bf(u.y); o[2] = f2bf(u.z); o[3] = f2bf(u.w);
            o[4] = f2bf(v.x); o[5] = f2bf(v.y); o[6] = f2bf(v.z); o[7] = f2bf(v.w);
            af[m][ks] = o;
        }

    // ---- x2 per row (np pairwise), 2 lanes/row, into LDS ----
    {
        int r = l >> 1, half = l & 1;
        const float4* xr4 = reinterpret_cast<const float4*>(X + (size_t)(wave_row0 + r) * D_DIM);
        auto ld = [&](int d4) { return xr4[d4]; };
        float v = np_pairwise_half(ld, half * 32);
        float other = __shfl_xor(v, 1);
        if (half == 0) x2L[w * 32 + r] = __fadd_rn(v, other);
    }
    __syncthreads();                         // drains stage 0; publishes c2s/x2L

    // per-lane top-2 per (m, j): positive-score-bits | col ; smaller = better
    unsigned t[2][4][2];
    #pragma unroll
    for (int m = 0; m < 2; ++m)
        #pragma unroll
        for (int j = 0; j < 4; ++j) { t[m][j][0] = 0xFFFFFFFFu; t[m][j][1] = 0xFFFFFFFFu; }

    // pipelined previous-step accumulators (score 2e30 never selected after 2 real inserts)
    f32x4 a0p = {-1e30f, -1e30f, -1e30f, -1e30f};
    f32x4 a1p = a0p;
    int   colp = lo16;

    #define INSERT_PREV() { \
        float ccp = c2s[colp]; \
        _Pragma("unroll") \
        for (int m = 0; m < 2; ++m) { \
            _Pragma("unroll") \
            for (int j = 0; j < 4; ++j) { \
                float s2 = fmaf(-2.0f, (m == 0 ? a0p[j] : a1p[j]), ccp); \
                unsigned p = (__float_as_uint(s2) & 0xFFFFFC00u) | (unsigned)colp; \
                unsigned o1 = min(t[m][j][1], max(p, t[m][j][0])); \
                unsigned o0 = min(t[m][j][0], p); \
                t[m][j][1] = o1; t[m][j][0] = o0; \
            } \
        } }

    for (int T = 0; T < NCT; ++T) {
        const int cur = T & 1;
        if (T + 1 < NCT) STAGE(cur ^ 1, T + 1);   // issue-early; lands during compute of T
        #pragma unroll
        for (int s = 0; s < 4; ++s) {
            int n = T * 4 + s;               // 16-col step 0..63
            bf16x8 bfv[8];
            #pragma unroll
            for (int ks = 0; ks < 8; ++ks)
                bfv[ks] = Bs[cur][s * 512 + ks * 64 + kg * 16 + lo16];
            f32x4 p0 = {0.f,0.f,0.f,0.f}, p1 = {0.f,0.f,0.f,0.f};
            f32x4 q0 = {0.f,0.f,0.f,0.f}, q1 = {0.f,0.f,0.f,0.f};
            #pragma unroll
            for (int ks = 0; ks < 4; ++ks) {
                p0 = __builtin_amdgcn_mfma_f32_16x16x32_bf16(af[0][ks],     bfv[ks],     p0, 0, 0, 0);
                q0 = __builtin_amdgcn_mfma_f32_16x16x32_bf16(af[1][ks],     bfv[ks],     q0, 0, 0, 0);
                p1 = __builtin_amdgcn_mfma_f32_16x16x32_bf16(af[0][ks + 4], bfv[ks + 4], p1, 0, 0, 0);
                q1 = __builtin_amdgcn_mfma_f32_16x16x32_bf16(af[1][ks + 4], bfv[ks + 4], q1, 0, 0, 0);
            }
            INSERT_PREV();                   // previous step's insert fills the MFMA shadow
            a0p = p0 + p1;
            a1p = q0 + q1;
            colp = n * 16 + lo16;
        }
        __syncthreads();                     // all done reading buf[cur]; stage T+1 landed
    }
    INSERT_PREV();                           // tail
    #undef INSERT_PREV
    #undef STAGE

    // ---- butterfly merge over 16 col-lanes: seed (top2, +inf, +inf) -> row top-4 ----
    #pragma unroll
    for (int m = 0; m < 2; ++m)
        #pragma unroll
        for (int j = 0; j < 4; ++j) {
            unsigned v0 = t[m][j][0], v1 = t[m][j][1];
            unsigned v2 = 0xFFFFFFFFu, v3 = 0xFFFFFFFFu;
            #pragma unroll
            for (int mask = 1; mask <= 8; mask <<= 1) {
                unsigned o0 = (unsigned)__shfl_xor((int)v0, mask);
                unsigned o1 = (unsigned)__shfl_xor((int)v1, mask);
                unsigned o2 = (unsigned)__shfl_xor((int)v2, mask);
                unsigned o3 = (unsigned)__shfl_xor((int)v3, mask);
                unsigned c0 = min(v0, o3), c1 = min(v1, o2), c2_ = min(v2, o1), c3 = min(v3, o0);
                unsigned lo, hi;
                lo = min(c0, c2_); hi = max(c0, c2_); c0 = lo; c2_ = hi;
                lo = min(c1, c3);  hi = max(c1, c3);  c1 = lo; c3  = hi;
                lo = min(c0, c1);  hi = max(c0, c1);  c0 = lo; c1  = hi;
                lo = min(c2_, c3); hi = max(c2_, c3); c2_ = lo; c3 = hi;
                v0 = c0; v1 = c1; v2 = c2_; v3 = c3;
            }
            if (lo16 == 0) {
                int rl = m * 16 + kg * 4 + j;
                candL[w * 32 + rl][0] = v0 & 1023u;
                candL[w * 32 + rl][1] = v1 & 1023u;
                candL[w * 32 + rl][2] = v2 & 1023u;
                candL[w * 32 + rl][3] = v3 & 1023u;
            }
        }
    __syncthreads();

    // ---- np-exact rescore: 512 chains on 256 threads, 2 chains interleaved per thread ----
    {
        int id0 = tid, id1 = tid + 256;
        int rr0 = id0 >> 2, c0 = id0 & 3;
        int rr1 = id1 >> 2, c1 = id1 & 3;
        int cand0 = (int)candL[rr0][c0];
        int cand1 = (int)candL[rr1][c1];
        const float4* x0 = reinterpret_cast<const float4*>(X + (size_t)(blk_row0 + rr0) * D_DIM);
        const float4* cr0 = reinterpret_cast<const float4*>(C + (size_t)cand0 * D_DIM);
        const float4* x1 = reinterpret_cast<const float4*>(X + (size_t)(blk_row0 + rr1) * D_DIM);
        const float4* cr1 = reinterpret_cast<const float4*>(C + (size_t)cand1 * D_DIM);
        float acc0 = 0.0f, acc1 = 0.0f;      // each chain keeps np-exact serial order
        #pragma unroll 4
        for (int d4 = 0; d4 < 64; ++d4) {
            float4 xa = x0[d4], ca = cr0[d4];
            float4 xb = x1[d4], cb = cr1[d4];
            acc0 = __fadd_rn(acc0, __fmul_rn(xa.x, ca.x));
            acc0 = __fadd_rn(acc0, __fmul_rn(xa.y, ca.y));
            acc0 = __fadd_rn(acc0, __fmul_rn(xa.z, ca.z));
            acc0 = __fadd_rn(acc0, __fmul_rn(xa.w, ca.w));
            acc1 = __fadd_rn(acc1, __fmul_rn(xb.x, cb.x));
            acc1 = __fadd_rn(acc1, __fmul_rn(xb.y, cb.y));
            acc1 = __fadd_rn(acc1, __fmul_rn(xb.z, cb.z));
            acc1 = __fadd_rn(acc1, __fmul_rn(xb.w, cb.w));
        }
        float s0 = __fadd_rn(__fsub_rn(x2L[rr0], __fmul_rn(2.0f, acc0)), c2g[cand0]);
        float s1 = __fadd_rn(__fsub_rn(x2L[rr1], __fmul_rn(2.0f, acc1)), c2g[cand1]);
        #pragma unroll
        for (int mm = 1; mm <= 2; mm <<= 1) {
            float os = __shfl_xor(s0, mm);
            int   oc = __shfl_xor(cand0, mm);
            if (os < s0 || (os == s0 && oc < cand0)) { s0 = os; cand0 = oc; }
        }
        #pragma unroll
        for (int mm = 1; mm <= 2; mm <<= 1) {
            float os = __shfl_xor(s1, mm);
            int   oc = __shfl_xor(cand1, mm);
            if (os < s1 || (os == s1 && oc < cand1)) { s1 = os; cand1 = oc; }
        }
        if (c0 == 0) asgL[rr0] = cand0;
        if (c1 == 0) asgL[rr1] = cand1;
    }
    __syncthreads();

    // ---- gather: out[row] = C[asg[row]], coalesced, nontemporal ----
    const f32x4* C4 = reinterpret_cast<const f32x4*>(C);
    f32x4* O4 = reinterpret_cast<f32x4*>(out) + (size_t)blk_row0 * 64;
    #pragma unroll
    for (int i = 0; i < 32; ++i) {
        int flat = tid + i * 256;            // 0..8191
        int r    = flat >> 6;
        int d4   = flat & 63;
        f32x4 v = C4[(size_t)asgL[r] * 64 + d4];
        __builtin_nontemporal_store(v, &O4[flat]);
    }
}

extern "C" void kernel_launch(void* const* d_in, const int* in_sizes, int n_in,
                              void* d_out, int out_size, void* d_ws, size_t ws_size,
                              hipStream_t stream) {
    const float* X = (const float*)d_in[0];
    const float* C = (const float*)d_in[1];
    float* out = (float*)d_out;

    char* ws = (char*)d_ws;
    float* c2 = (float*)ws;                        // 4 KB
    short* Cs = (short*)(ws + 4096);               // 512 KB swizzled bf16 C

    int N = in_sizes[0] / D_DIM;                   // 65536

    prep_kernel<<<(K_CL * D_DIM / 8) / 256, 256, 0, stream>>>(C, Cs, c2);
    kmeans_fused<<<N / BN, 256, 0, stream>>>(X, C, Cs, c2, out);
}

// Round 23
// 73.045 us; speedup vs baseline: 1.5139x; 1.5139x over previous
//
#include <hip/hip_runtime.h>

#define K_CL  1024
#define D_DIM 256
#define BN    128                 // rows per block (4 waves x 32 rows)
#define CTILE 128                 // cols per staged LDS tile (64 KB)
#define NCT   (K_CL / CTILE)      // 8 tiles

typedef __attribute__((ext_vector_type(8))) short bf16x8;
typedef __attribute__((ext_vector_type(4))) float f32x4;

// ---------- fp32 -> bf16 round-to-nearest-even ----------
__device__ __forceinline__ short f2bf(float f) {
    unsigned b = __float_as_uint(f);
    unsigned r = (b + 0x7FFFu + ((b >> 16) & 1u)) >> 16;
    return (short)r;
}

// ---------- async global->LDS, 16B per lane ----------
__device__ __forceinline__ void gload_lds16(const void* g, void* l) {
    __builtin_amdgcn_global_load_lds(
        (const __attribute__((address_space(1))) unsigned int*)g,
        (__attribute__((address_space(3))) unsigned int*)l, 16, 0, 0);
}

// ---------- numpy pairwise sum-of-squares (np-exact; contract(off) forbids fma) ----------
template <typename F>
__device__ float np_pairwise_half(F ld, int base4) {
#pragma clang fp contract(off)
    float4 f0 = ld(base4 + 0);
    float4 f1 = ld(base4 + 1);
    float r0 = __fmul_rn(f0.x, f0.x), r1 = __fmul_rn(f0.y, f0.y);
    float r2 = __fmul_rn(f0.z, f0.z), r3 = __fmul_rn(f0.w, f0.w);
    float r4 = __fmul_rn(f1.x, f1.x), r5 = __fmul_rn(f1.y, f1.y);
    float r6 = __fmul_rn(f1.z, f1.z), r7 = __fmul_rn(f1.w, f1.w);
    #pragma unroll
    for (int p = 1; p < 16; ++p) {
        float4 a = ld(base4 + 2 * p);
        float4 b = ld(base4 + 2 * p + 1);
        r0 = __fadd_rn(r0, __fmul_rn(a.x, a.x)); r1 = __fadd_rn(r1, __fmul_rn(a.y, a.y));
        r2 = __fadd_rn(r2, __fmul_rn(a.z, a.z)); r3 = __fadd_rn(r3, __fmul_rn(a.w, a.w));
        r4 = __fadd_rn(r4, __fmul_rn(b.x, b.x)); r5 = __fadd_rn(r5, __fmul_rn(b.y, b.y));
        r6 = __fadd_rn(r6, __fmul_rn(b.z, b.z)); r7 = __fadd_rn(r7, __fmul_rn(b.w, b.w));
    }
    return __fadd_rn(__fadd_rn(__fadd_rn(r0, r1), __fadd_rn(r2, r3)),
                     __fadd_rn(__fadd_rn(r4, r5), __fadd_rn(r6, r7)));
}

// ---- kernel 1: cvt (C fp32 -> swizzled bf16) + c2 (blocks 0..7) ----
__global__ void prep_kernel(const float* __restrict__ C, short* __restrict__ Cs,
                            float* __restrict__ c2) {
#pragma clang fp contract(off)
    int d    = blockIdx.x * 256 + threadIdx.x;     // 0..32767
    int n    = d >> 9;
    int r    = d & 511;
    int ks   = r >> 6;
    int kg   = (r >> 4) & 3;
    int lo   = r & 15;
    int col  = n * 16 + lo;
    const float* src = C + (size_t)col * D_DIM + ks * 32 + kg * 8;
    float4 a = *reinterpret_cast<const float4*>(src);
    float4 b = *reinterpret_cast<const float4*>(src + 4);
    bf16x8 o;
    o[0] = f2bf(a.x); o[1] = f2bf(a.y); o[2] = f2bf(a.z); o[3] = f2bf(a.w);
    o[4] = f2bf(b.x); o[5] = f2bf(b.y); o[6] = f2bf(b.z); o[7] = f2bf(b.w);
    reinterpret_cast<bf16x8*>(Cs)[d] = o;

    if (blockIdx.x < 8) {
        int id   = blockIdx.x * 128 + (threadIdx.x >> 1);   // row k
        int half = threadIdx.x & 1;
        const float4* row = reinterpret_cast<const float4*>(C) + (size_t)id * 64;
        auto ld = [&](int d4) { return row[d4]; };
        float v = np_pairwise_half(ld, half * 32);
        float other = __shfl_xor(v, 1);
        if (half == 0) c2[id] = __fadd_rn(v, other);
    }
}

// ---- kernel 2: fused gemm (R21 core) + margin-gated np-exact rescore + gather ----
__launch_bounds__(256, 2)
__global__ void kmeans_fused(const float* __restrict__ X, const float* __restrict__ C,
                             const short* __restrict__ Cswz, const float* __restrict__ c2g,
                             float* __restrict__ out) {
#pragma clang fp contract(off)
    __shared__ bf16x8   Bs[CTILE * 32];      // 64 KB
    __shared__ float    c2s[K_CL];           // 4 KB, pre-offset by +32
    __shared__ float    x2L[BN];
    __shared__ unsigned candL[BN][4];
    __shared__ int      asgL[BN];
    __shared__ int      needL[BN];
    __shared__ int      cntL;

    const int tid  = threadIdx.x;
    const int w    = tid >> 6;               // wave 0..3
    const int l    = tid & 63;
    const int lo16 = l & 15;
    const int kg   = l >> 4;
    const int blk_row0  = blockIdx.x * BN;
    const int wave_row0 = blk_row0 + w * 32; // 32 rows per wave (2 m-frags)

    const bf16x8* Cs8 = reinterpret_cast<const bf16x8*>(Cswz);

    if (tid == 0) cntL = 0;                  // published by the prologue barrier

    // c2s with +32 offset: scores provably positive -> float bits monotone
    #pragma unroll
    for (int i = 0; i < 4; ++i) c2s[tid + i * 256] = __fadd_rn(c2g[tid + i * 256], 32.0f);

    // ---- resident A fragments ----
    bf16x8 af[2][8];
    #pragma unroll
    for (int m = 0; m < 2; ++m)
        #pragma unroll
        for (int ks = 0; ks < 8; ++ks) {
            const float* xr = X + (size_t)(wave_row0 + m * 16 + lo16) * D_DIM + ks * 32 + kg * 8;
            float4 u = *reinterpret_cast<const float4*>(xr);
            float4 v = *reinterpret_cast<const float4*>(xr + 4);
            bf16x8 o;
            o[0] = f2bf(u.x); o[1] = f2bf(u.y); o[2] = f2bf(u.z); o[3] = f2bf(u.w);
            o[4] = f2bf(v.x); o[5] = f2bf(v.y); o[6] = f2bf(v.z); o[7] = f2bf(v.w);
            af[m][ks] = o;
        }

    // ---- x2 per row (np pairwise), 2 lanes/row, into LDS ----
    {
        int r = l >> 1, half = l & 1;
        const float4* xr4 = reinterpret_cast<const float4*>(X + (size_t)(wave_row0 + r) * D_DIM);
        auto ld = [&](int d4) { return xr4[d4]; };
        float v = np_pairwise_half(ld, half * 32);
        float other = __shfl_xor(v, 1);
        if (half == 0) x2L[w * 32 + r] = __fadd_rn(v, other);
    }

    // per-lane top-2 per (m, j): positive-score-bits | col ; smaller = better
    unsigned t[2][4][2];
    #pragma unroll
    for (int m = 0; m < 2; ++m)
        #pragma unroll
        for (int j = 0; j < 4; ++j) { t[m][j][0] = 0xFFFFFFFFu; t[m][j][1] = 0xFFFFFFFFu; }

    // pipelined previous-step accumulators (score 2e30 never selected)
    f32x4 a0p = {-1e30f, -1e30f, -1e30f, -1e30f};
    f32x4 a1p = a0p;
    int   colp = lo16;

    #define INSERT_PREV() { \
        float ccp = c2s[colp]; \
        _Pragma("unroll") \
        for (int m = 0; m < 2; ++m) { \
            _Pragma("unroll") \
            for (int j = 0; j < 4; ++j) { \
                float s2 = fmaf(-2.0f, (m == 0 ? a0p[j] : a1p[j]), ccp); \
                unsigned p = (__float_as_uint(s2) & 0xFFFFFC00u) | (unsigned)colp; \
                unsigned o1 = min(t[m][j][1], max(p, t[m][j][0])); \
                unsigned o0 = min(t[m][j][0], p); \
                t[m][j][1] = o1; t[m][j][0] = o0; \
            } \
        } }

    for (int Tc = 0; Tc < NCT; ++Tc) {
        __syncthreads();                     // all waves done reading previous tile
        {
            const bf16x8* gsrc = Cs8 + (size_t)Tc * (CTILE * 32);
            #pragma unroll
            for (int c = 0; c < 16; ++c)
                gload_lds16(&gsrc[c * 256 + tid], &Bs[c * 256 + tid]);
        }
        __syncthreads();                     // staged; 8 free-run n-steps follow

        #pragma unroll
        for (int s = 0; s < 8; ++s) {
            int n = Tc * 8 + s;
            bf16x8 bfv[8];
            #pragma unroll
            for (int ks = 0; ks < 8; ++ks)
                bfv[ks] = Bs[s * 512 + ks * 64 + kg * 16 + lo16];
            f32x4 p0 = {0.f,0.f,0.f,0.f}, p1 = {0.f,0.f,0.f,0.f};
            f32x4 q0 = {0.f,0.f,0.f,0.f}, q1 = {0.f,0.f,0.f,0.f};
            #pragma unroll
            for (int ks = 0; ks < 4; ++ks) {
                p0 = __builtin_amdgcn_mfma_f32_16x16x32_bf16(af[0][ks],     bfv[ks],     p0, 0, 0, 0);
                q0 = __builtin_amdgcn_mfma_f32_16x16x32_bf16(af[1][ks],     bfv[ks],     q0, 0, 0, 0);
                p1 = __builtin_amdgcn_mfma_f32_16x16x32_bf16(af[0][ks + 4], bfv[ks + 4], p1, 0, 0, 0);
                q1 = __builtin_amdgcn_mfma_f32_16x16x32_bf16(af[1][ks + 4], bfv[ks + 4], q1, 0, 0, 0);
            }
            INSERT_PREV();                   // previous step's insert fills the MFMA shadow
            a0p = p0 + p1;
            a1p = q0 + q1;
            colp = n * 16 + lo16;
        }
    }
    INSERT_PREV();                           // tail
    #undef INSERT_PREV

    // ---- butterfly merge over 16 col-lanes -> row top-4; margin-gate the rescore ----
    #pragma unroll
    for (int m = 0; m < 2; ++m)
        #pragma unroll
        for (int j = 0; j < 4; ++j) {
            unsigned v0 = t[m][j][0], v1 = t[m][j][1];
            unsigned v2 = 0xFFFFFFFFu, v3 = 0xFFFFFFFFu;
            #pragma unroll
            for (int mask = 1; mask <= 8; mask <<= 1) {
                unsigned o0 = (unsigned)__shfl_xor((int)v0, mask);
                unsigned o1 = (unsigned)__shfl_xor((int)v1, mask);
                unsigned o2 = (unsigned)__shfl_xor((int)v2, mask);
                unsigned o3 = (unsigned)__shfl_xor((int)v3, mask);
                unsigned c0 = min(v0, o3), c1 = min(v1, o2), c2_ = min(v2, o1), c3 = min(v3, o0);
                unsigned lo, hi;
                lo = min(c0, c2_); hi = max(c0, c2_); c0 = lo; c2_ = hi;
                lo = min(c1, c3);  hi = max(c1, c3);  c1 = lo; c3  = hi;
                lo = min(c0, c1);  hi = max(c0, c1);  c0 = lo; c1  = hi;
                lo = min(c2_, c3); hi = max(c2_, c3); c2_ = lo; c3 = hi;
                v0 = c0; v1 = c1; v2 = c2_; v3 = c3;
            }
            if (lo16 == 0) {
                int rl  = m * 16 + kg * 4 + j;
                int row = w * 32 + rl;
                candL[row][0] = v0 & 1023u;
                candL[row][1] = v1 & 1023u;
                candL[row][2] = v2 & 1023u;
                candL[row][3] = v3 & 1023u;
                // fast-score gap (packed-truncated, positive-monotone bits)
                float g = __fsub_rn(__uint_as_float(v1 & 0xFFFFFC00u),
                                    __uint_as_float(v0 & 0xFFFFFC00u));
                // bound: |np_gap - g| <= 2*trunc(3.9e-3) + fast<->np error (~1e-2) << 0.06
                if (g >= 0.06f) {
                    asgL[row] = (int)(v0 & 1023u);   // np winner certain = fast winner
                } else {
                    int slot = atomicAdd(&cntL, 1);  // LDS atomic, block-local
                    needL[slot] = row;
                }
            }
        }
    __syncthreads();

    // ---- np-exact rescore, only for compacted needy rows (4 chains/row) ----
    {
        int M = cntL;
        #pragma unroll
        for (int slot = 0; slot < 2; ++slot) {
            int id = slot * 256 + tid;
            if (id < 4 * M) {
                int rr   = needL[id >> 2];           // row within block
                int c    = id & 3;
                int cand = (int)candL[rr][c];
                const float4* xr4 = reinterpret_cast<const float4*>(X + (size_t)(blk_row0 + rr) * D_DIM);
                const float4* cr4 = reinterpret_cast<const float4*>(C + (size_t)cand * D_DIM);
                float acc = 0.0f;                    // np-exact serial order
                #pragma unroll 8
                for (int d4 = 0; d4 < 64; ++d4) {
                    float4 xv = xr4[d4], cv = cr4[d4];
                    acc = __fadd_rn(acc, __fmul_rn(xv.x, cv.x));
                    acc = __fadd_rn(acc, __fmul_rn(xv.y, cv.y));
                    acc = __fadd_rn(acc, __fmul_rn(xv.z, cv.z));
                    acc = __fadd_rn(acc, __fmul_rn(xv.w, cv.w));
                }
                float sc = __fadd_rn(__fsub_rn(x2L[rr], __fmul_rn(2.0f, acc)), c2g[cand]);
                // winner among the 4 chain-lanes of this row (lanes 4r..4r+3 contiguous)
                #pragma unroll
                for (int mm = 1; mm <= 2; mm <<= 1) {
                    float os = __shfl_xor(sc, mm);
                    int   oc = __shfl_xor(cand, mm);
                    if (os < sc || (os == sc && oc < cand)) { sc = os; cand = oc; }
                }
                if (c == 0) asgL[rr] = cand;
            }
        }
    }
    __syncthreads();

    // ---- gather: out[row] = C[asg[row]], coalesced, nontemporal ----
    const f32x4* C4 = reinterpret_cast<const f32x4*>(C);
    f32x4* O4 = reinterpret_cast<f32x4*>(out) + (size_t)blk_row0 * 64;
    #pragma unroll
    for (int i = 0; i < 32; ++i) {
        int flat = tid + i * 256;            // 0..8191
        int r    = flat >> 6;
        int d4   = flat & 63;
        f32x4 v = C4[(size_t)asgL[r] * 64 + d4];
        __builtin_nontemporal_store(v, &O4[flat]);
    }
}

extern "C" void kernel_launch(void* const* d_in, const int* in_sizes, int n_in,
                              void* d_out, int out_size, void* d_ws, size_t ws_size,
                              hipStream_t stream) {
    const float* X = (const float*)d_in[0];
    const float* C = (const float*)d_in[1];
    float* out = (float*)d_out;

    char* ws = (char*)d_ws;
    float* c2 = (float*)ws;                        // 4 KB
    short* Cs = (short*)(ws + 4096);               // 512 KB swizzled bf16 C

    int N = in_sizes[0] / D_DIM;                   // 65536

    prep_kernel<<<(K_CL * D_DIM / 8) / 256, 256, 0, stream>>>(C, Cs, c2);
    kmeans_fused<<<N / BN, 256, 0, stream>>>(X, C, Cs, c2, out);
}